// Round 3
// baseline (302.815 us; speedup 1.0000x reference)
//
#include <hip/hip_runtime.h>
#include <stdint.h>

#define M_DIM 16384
#define N_DIM 4096
#define K_DIM 512

typedef int v8i __attribute__((ext_vector_type(8)));
typedef float f32x16 __attribute__((ext_vector_type(16)));
typedef float f32x4v __attribute__((ext_vector_type(4)));

typedef __attribute__((address_space(3))) uint32_t lds_u32_t;
typedef const __attribute__((address_space(1))) uint32_t glob_u32_t;

__device__ __forceinline__ void gload16(const void* g, void* l) {
    __builtin_amdgcn_global_load_lds((glob_u32_t*)g, (lds_u32_t*)l, 16, 0, 0);
}

// Convert fp32 -> fp8 e4m3 + row sums of squares.  (UNCHANGED from round 2:
// r0-scatter vs r2-coalesced stores measured identical (-0.4 us) -> convert is
// launch/latency-bound at <=30 us, not worth further churn.)
__global__ __launch_bounds__(256)
void convert_norm_kernel(const float* __restrict__ X, const float* __restrict__ C,
                         uint8_t* __restrict__ Apack, uint8_t* __restrict__ Bf8,
                         float* __restrict__ xsq, float* __restrict__ csq) {
    const int bid = blockIdx.x;
    const int t = threadIdx.x;

    if (bid < 512) {
        // ---- A slab path ----
        __shared__ float sums[4][32];
        const int P = bid;
        const int r = (t >> 1) & 31;
        const int w = t >> 6;
        const float* Xs = X + (size_t)P * 32 * K_DIM;
        uint8_t* dst = Apack + (size_t)P * 16384;
        float s = 0.f;
        #pragma unroll
        for (int i = 0; i < 4; ++i) {
            const int q = i * 256 + t;
            const int c0 = (q >> 7) * 64 + ((q >> 6) & 1) * 32 + (q & 1) * 16;
            const float4* p = (const float4*)(Xs + (size_t)r * K_DIM + c0);
            float4 f0 = p[0], f1 = p[1], f2 = p[2], f3 = p[3];
            uint32_t d0 = 0, d1 = 0, d2 = 0, d3 = 0;
            d0 = __builtin_amdgcn_cvt_pk_fp8_f32(f0.x, f0.y, d0, false);
            d0 = __builtin_amdgcn_cvt_pk_fp8_f32(f0.z, f0.w, d0, true);
            d1 = __builtin_amdgcn_cvt_pk_fp8_f32(f1.x, f1.y, d1, false);
            d1 = __builtin_amdgcn_cvt_pk_fp8_f32(f1.z, f1.w, d1, true);
            d2 = __builtin_amdgcn_cvt_pk_fp8_f32(f2.x, f2.y, d2, false);
            d2 = __builtin_amdgcn_cvt_pk_fp8_f32(f2.z, f2.w, d2, true);
            d3 = __builtin_amdgcn_cvt_pk_fp8_f32(f3.x, f3.y, d3, false);
            d3 = __builtin_amdgcn_cvt_pk_fp8_f32(f3.z, f3.w, d3, true);
            *(uint4*)(dst + (size_t)q * 16) = make_uint4(d0, d1, d2, d3);
            s += f0.x*f0.x + f0.y*f0.y + f0.z*f0.z + f0.w*f0.w
               + f1.x*f1.x + f1.y*f1.y + f1.z*f1.z + f1.w*f1.w
               + f2.x*f2.x + f2.y*f2.y + f2.z*f2.z + f2.w*f2.w
               + f3.x*f3.x + f3.y*f3.y + f3.z*f3.z + f3.w*f3.w;
        }
        s += __shfl_xor(s, 1, 64);
        if ((t & 1) == 0) sums[w][r] = s;
        __syncthreads();
        if (t < 32)
            xsq[P * 32 + t] = sums[0][t] + sums[1][t] + sums[2][t] + sums[3][t];
    } else {
        // ---- B row path (row-major, wave per row) ----
        const int wave = t >> 6;
        const int lane = t & 63;
        const int rr = (bid - 512) * 4 + wave;
        const float4* p = (const float4*)(C + (size_t)rr * K_DIM) + lane * 2;
        float4 a = p[0], b = p[1];
        uint32_t lo = 0, hi = 0;
        lo = __builtin_amdgcn_cvt_pk_fp8_f32(a.x, a.y, lo, false);
        lo = __builtin_amdgcn_cvt_pk_fp8_f32(a.z, a.w, lo, true);
        hi = __builtin_amdgcn_cvt_pk_fp8_f32(b.x, b.y, hi, false);
        hi = __builtin_amdgcn_cvt_pk_fp8_f32(b.z, b.w, hi, true);
        *(uint2*)(Bf8 + (size_t)rr * K_DIM + lane * 8) = make_uint2(lo, hi);

        float s = a.x*a.x + a.y*a.y + a.z*a.z + a.w*a.w
                + b.x*b.x + b.y*b.y + b.z*b.z + b.w*b.w;
        #pragma unroll
        for (int o2 = 32; o2 > 0; o2 >>= 1) s += __shfl_down(s, o2, 64);
        if (lane == 0) csq[rr] = s;
    }
}

// v3: Block 128x128, 4 waves each 32x128 (mfma_scale 32x32x64 fp8, acc=64 VGPR).
// FULL-B LDS (64 KB = four 16-KB kk-segments, staged once) + ONE barrier total.
// r0's structure (61.2 us measured) had 7 barriers/block, each a full vmcnt(0)
// drain -> per-generation write-idle windows + store bursts (~18 us over the
// ~43-48 us NT-write floor). Here: A fragments (all 8 ks, 64 VGPR), cs4 and the
// 4 xs4 epilogue operands are all loaded BEFORE the single barrier (its
// structural drain hides their latency at zero cost); after the barrier the
// K-loop is barrier-free and waitcnt-free except ds_read lgkmcnt -> waves drift,
// stores pace continuously. LDS 64 KB -> 2 blocks/CU (launch_bounds(256,2)
// opens the VGPR budget to 256; demand ~190).
// Per-kk-segment LDS map unchanged from r0 (verified absmax 0.0):
//   segment kk at Bs+kk*16384; within: row p (128 B) <-> global col
//   bn + 4*(p&31) + (p>>5); chunk c of row p at slot (c+p)&7 -> conflict-free
//   ds_read_b128, swizzle cancels at read. Accumulation order kk->ksl->j
//   identical to r0 -> bit-identical output.
__global__ __launch_bounds__(256, 2)
void rbf_mfma_kernel(const uint8_t* __restrict__ Apack, const uint8_t* __restrict__ B8,
                     const float* __restrict__ xsq, const float* __restrict__ csq,
                     float* __restrict__ out) {
    __shared__ uint8_t Bs[4 * 128 * 128];   // 64 KB

    const int tid = threadIdx.x;
    const int lv  = tid & 63;
    const int w   = tid >> 6;
    const int h   = lv >> 5;
    const int r31 = lv & 31;

    const int bn = (blockIdx.x & 31) * 128;   // bn fastest -> A-slab L2 reuse
    const int bm = (blockIdx.x >> 5) * 128;

    // ---- B staging: all 4 kk segments, one barrier ----
    const int tr = tid >> 3;            // 0..31
    const int tc = tid & 7;
    const int cc = (tc - tr) & 7;
    const uint8_t* gB = B8 + (size_t)(bn + 4 * tr) * K_DIM + cc * 16;
    uint8_t* BsW = Bs + w * 1024;

    #pragma unroll
    for (int kk = 0; kk < 4; ++kk)
        #pragma unroll
        for (int R = 0; R < 4; ++R)
            gload16(gB + kk * 128 + (size_t)R * K_DIM, BsW + kk * 16384 + R * 4096);

    // ---- A fragments for ALL 8 ks, issued before the barrier ----
    const uint8_t* aB = Apack + (size_t)((bm >> 5) + w) * 16384 + h * 1024 + r31 * 32;
    uint4 a0[8], a1[8];
    #pragma unroll
    for (int ks = 0; ks < 8; ++ks) {
        const uint8_t* ap = aB + ks * 2048;
        a0[ks] = *(const uint4*)(ap);
        a1[ks] = *(const uint4*)(ap + 16);
    }

    // ---- epilogue operands, also pre-barrier ----
    const float4 cs4 = *(const float4*)(csq + bn + 4 * r31);
    const int mbase = bm + 32 * w + 4 * h;
    float4 xs4[4];
    #pragma unroll
    for (int g = 0; g < 4; ++g)
        xs4[g] = *(const float4*)(xsq + mbase + 8 * g);

    __syncthreads();   // the ONLY barrier: drains B staging + A/epilogue loads

    const uint8_t* bRow = Bs + r31 * 128;
    f32x16 acc[4] = {};   // 64 VGPRs

    #pragma unroll
    for (int kk = 0; kk < 4; ++kk) {
        #pragma unroll
        for (int ksl = 0; ksl < 2; ++ksl) {
            const int ks = 2 * kk + ksl;
            v8i av = (v8i){(int)a0[ks].x, (int)a0[ks].y, (int)a0[ks].z, (int)a0[ks].w,
                           (int)a1[ks].x, (int)a1[ks].y, (int)a1[ks].z, (int)a1[ks].w};
            const int c0 = ksl * 4 + 2 * h;
            const int s0 = ((c0 + 0 + r31) & 7) * 16;
            const int s1 = ((c0 + 1 + r31) & 7) * 16;
            #pragma unroll
            for (int j = 0; j < 4; ++j) {
                const uint8_t* seg = bRow + kk * 16384 + j * 4096;
                uint4 lo = *(const uint4*)(seg + s0);
                uint4 hi = *(const uint4*)(seg + s1);
                v8i bv = (v8i){(int)lo.x, (int)lo.y, (int)lo.z, (int)lo.w,
                               (int)hi.x, (int)hi.y, (int)hi.z, (int)hi.w};
                acc[j] = __builtin_amdgcn_mfma_scale_f32_32x32x64_f8f6f4(
                    av, bv, acc[j],
                    0 /*fp8*/, 0 /*fp8*/,
                    0, 0x7F7F7F7Fu, 0, 0x7F7F7F7Fu);
            }
        }
    }

    // ---- epilogue: out = exp(-(xsq - 2*cross + csq)), float4 NT stores ----
    // C/D 32x32: col = lane&31 -> global col bn + 4*r31 + j (col interleave);
    // row = (reg&3) + 8*(reg>>2) + 4h
    #pragma unroll
    for (int g = 0; g < 4; ++g) {
        #pragma unroll
        for (int rr = 0; rr < 4; ++rr) {
            const int reg = g * 4 + rr;
            const float xs = (rr == 0) ? xs4[g].x : (rr == 1) ? xs4[g].y
                           : (rr == 2) ? xs4[g].z : xs4[g].w;
            const int gm = mbase + 8 * g + rr;
            f32x4v o;
            o.x = __expf(-(xs - 2.0f * acc[0][reg] + cs4.x));
            o.y = __expf(-(xs - 2.0f * acc[1][reg] + cs4.y));
            o.z = __expf(-(xs - 2.0f * acc[2][reg] + cs4.z));
            o.w = __expf(-(xs - 2.0f * acc[3][reg] + cs4.w));
            __builtin_nontemporal_store(
                o, (f32x4v*)(out + (size_t)gm * N_DIM + bn + 4 * r31));
        }
    }
}

extern "C" void kernel_launch(void* const* d_in, const int* in_sizes, int n_in,
                              void* d_out, int out_size, void* d_ws, size_t ws_size,
                              hipStream_t stream) {
    const float* X = (const float*)d_in[0];
    const float* C = (const float*)d_in[1];
    float* out = (float*)d_out;

    uint8_t* Apack = (uint8_t*)d_ws;                          // 8 MB
    uint8_t* Bf8 = Apack + (size_t)M_DIM * K_DIM;             // 2 MB
    float* xsq = (float*)(Bf8 + (size_t)N_DIM * K_DIM);       // 64 KB
    float* csq = xsq + M_DIM;                                 // 16 KB

    convert_norm_kernel<<<512 + N_DIM / 4, 256, 0, stream>>>(X, C, Apack, Bf8, xsq, csq);
    rbf_mfma_kernel<<<(M_DIM / 128) * (N_DIM / 128), 256, 0, stream>>>(Apack, Bf8, xsq, csq, out);
}

// Round 5
// 296.148 us; speedup vs baseline: 1.0225x; 1.0225x over previous
//
#include <hip/hip_runtime.h>
#include <stdint.h>

#define M_DIM 16384
#define N_DIM 4096
#define K_DIM 512

typedef int v8i __attribute__((ext_vector_type(8)));
typedef float f32x16 __attribute__((ext_vector_type(16)));
typedef float f32x4v __attribute__((ext_vector_type(4)));

typedef __attribute__((address_space(3))) uint32_t lds_u32_t;
typedef const __attribute__((address_space(1))) uint32_t glob_u32_t;

__device__ __forceinline__ void gload16(const void* g, void* l) {
    __builtin_amdgcn_global_load_lds((glob_u32_t*)g, (lds_u32_t*)l, 16, 0, 0);
}

// Convert fp32 -> fp8 e4m3 + row sums of squares.  (UNCHANGED from round 2:
// scatter vs coalesced stores measured identical -> convert is not
// pattern-bound; leave it alone.)
__global__ __launch_bounds__(256)
void convert_norm_kernel(const float* __restrict__ X, const float* __restrict__ C,
                         uint8_t* __restrict__ Apack, uint8_t* __restrict__ Bf8,
                         float* __restrict__ xsq, float* __restrict__ csq) {
    const int bid = blockIdx.x;
    const int t = threadIdx.x;

    if (bid < 512) {
        // ---- A slab path ----
        __shared__ float sums[4][32];
        const int P = bid;
        const int r = (t >> 1) & 31;
        const int w = t >> 6;
        const float* Xs = X + (size_t)P * 32 * K_DIM;
        uint8_t* dst = Apack + (size_t)P * 16384;
        float s = 0.f;
        #pragma unroll
        for (int i = 0; i < 4; ++i) {
            const int q = i * 256 + t;
            const int c0 = (q >> 7) * 64 + ((q >> 6) & 1) * 32 + (q & 1) * 16;
            const float4* p = (const float4*)(Xs + (size_t)r * K_DIM + c0);
            float4 f0 = p[0], f1 = p[1], f2 = p[2], f3 = p[3];
            uint32_t d0 = 0, d1 = 0, d2 = 0, d3 = 0;
            d0 = __builtin_amdgcn_cvt_pk_fp8_f32(f0.x, f0.y, d0, false);
            d0 = __builtin_amdgcn_cvt_pk_fp8_f32(f0.z, f0.w, d0, true);
            d1 = __builtin_amdgcn_cvt_pk_fp8_f32(f1.x, f1.y, d1, false);
            d1 = __builtin_amdgcn_cvt_pk_fp8_f32(f1.z, f1.w, d1, true);
            d2 = __builtin_amdgcn_cvt_pk_fp8_f32(f2.x, f2.y, d2, false);
            d2 = __builtin_amdgcn_cvt_pk_fp8_f32(f2.z, f2.w, d2, true);
            d3 = __builtin_amdgcn_cvt_pk_fp8_f32(f3.x, f3.y, d3, false);
            d3 = __builtin_amdgcn_cvt_pk_fp8_f32(f3.z, f3.w, d3, true);
            *(uint4*)(dst + (size_t)q * 16) = make_uint4(d0, d1, d2, d3);
            s += f0.x*f0.x + f0.y*f0.y + f0.z*f0.z + f0.w*f0.w
               + f1.x*f1.x + f1.y*f1.y + f1.z*f1.z + f1.w*f1.w
               + f2.x*f2.x + f2.y*f2.y + f2.z*f2.z + f2.w*f2.w
               + f3.x*f3.x + f3.y*f3.y + f3.z*f3.z + f3.w*f3.w;
        }
        s += __shfl_xor(s, 1, 64);
        if ((t & 1) == 0) sums[w][r] = s;
        __syncthreads();
        if (t < 32)
            xsq[P * 32 + t] = sums[0][t] + sums[1][t] + sums[2][t] + sums[3][t];
    } else {
        // ---- B row path (row-major, wave per row) ----
        const int wave = t >> 6;
        const int lane = t & 63;
        const int rr = (bid - 512) * 4 + wave;
        const float4* p = (const float4*)(C + (size_t)rr * K_DIM) + lane * 2;
        float4 a = p[0], b = p[1];
        uint32_t lo = 0, hi = 0;
        lo = __builtin_amdgcn_cvt_pk_fp8_f32(a.x, a.y, lo, false);
        lo = __builtin_amdgcn_cvt_pk_fp8_f32(a.z, a.w, lo, true);
        hi = __builtin_amdgcn_cvt_pk_fp8_f32(b.x, b.y, hi, false);
        hi = __builtin_amdgcn_cvt_pk_fp8_f32(b.z, b.w, hi, true);
        *(uint2*)(Bf8 + (size_t)rr * K_DIM + lane * 8) = make_uint2(lo, hi);

        float s = a.x*a.x + a.y*a.y + a.z*a.z + a.w*a.w
                + b.x*b.x + b.y*b.y + b.z*b.z + b.w*b.w;
        #pragma unroll
        for (int o2 = 32; o2 > 0; o2 >>= 1) s += __shfl_down(s, o2, 64);
        if (lane == 0) csq[rr] = s;
    }
}

// v4: r0 structure EXACTLY (16 KB B-LDS, 4 blk/CU, per-kk staging+barriers —
// measured 61.2 us; the 1-barrier/64KB variant was +2) with ONE change:
// bijective XCD swizzle on the block index. Mechanism: mfma is pinned by the
// mixed HBM stream (~5.3 TB/s measured in r1); traffic = 268 MB store (fixed)
// + ~80 MB fetch because default round-robin dispatch makes every XCD stream
// the full A (8 MB) + B (2 MB) panels from HBM. sw = (bid&7)*512 + (bid>>3)
// gives each XCD a contiguous 16-bm x 32-bn panel: working set 1 MB A + 2 MB B
// < 4 MB L2 -> fetch ~25-30 MB. Predict mfma 61 -> ~53 us.
// (4096 % 8 == 0 -> this swizzle is bijective; bn remains fastest within XCD.)
__global__ __launch_bounds__(256, 4)
void rbf_mfma_kernel(const uint8_t* __restrict__ Apack, const uint8_t* __restrict__ B8,
                     const float* __restrict__ xsq, const float* __restrict__ csq,
                     float* __restrict__ out) {
    __shared__ uint8_t Bs[128 * 128];   // 16 KB

    const int tid = threadIdx.x;
    const int lv  = tid & 63;
    const int w   = tid >> 6;
    const int h   = lv >> 5;
    const int r31 = lv & 31;

    const int sw = (blockIdx.x & 7) * 512 + (blockIdx.x >> 3);   // XCD swizzle
    const int bn = (sw & 31) * 128;   // bn fastest within an XCD's panel
    const int bm = (sw >> 5) * 128;

    // ---- B staging map ----
    const int tr = tid >> 3;            // 0..31
    const int tc = tid & 7;
    const int cc = (tc - tr) & 7;
    const uint8_t* gB = B8 + (size_t)(bn + 4 * tr) * K_DIM + cc * 16;
    uint8_t* BsW = Bs + w * 1024;

    // ---- A fragment base (wave-private 32-row slab, packed) ----
    const uint8_t* aB = Apack + (size_t)((bm >> 5) + w) * 16384 + h * 1024 + r31 * 32;

    const uint8_t* bRow = Bs + r31 * 128;

    f32x16 acc[4] = {};   // 64 VGPRs

    for (int kk = 0; kk < 4; ++kk) {
        const int koff = kk * 128;
        #pragma unroll
        for (int R = 0; R < 4; ++R)
            gload16(gB + koff + (size_t)R * K_DIM, BsW + R * 4096);

        // A loads for this kk — issued before the barrier; its vmcnt(0) drain
        // (structural) covers their L2 latency at zero extra cost.
        uint4 a0[2], a1[2];
        #pragma unroll
        for (int ksl = 0; ksl < 2; ++ksl) {
            const uint8_t* ap = aB + (2 * kk + ksl) * 2048;
            a0[ksl] = *(const uint4*)(ap);
            a1[ksl] = *(const uint4*)(ap + 16);
        }
        __syncthreads();

        #pragma unroll
        for (int ksl = 0; ksl < 2; ++ksl) {
            v8i av = (v8i){(int)a0[ksl].x, (int)a0[ksl].y, (int)a0[ksl].z, (int)a0[ksl].w,
                           (int)a1[ksl].x, (int)a1[ksl].y, (int)a1[ksl].z, (int)a1[ksl].w};
            const int c0 = ksl * 4 + 2 * h;
            const int s0 = ((c0 + 0 + r31) & 7) * 16;
            const int s1 = ((c0 + 1 + r31) & 7) * 16;
            #pragma unroll
            for (int j = 0; j < 4; ++j) {
                uint4 lo = *(const uint4*)(bRow + j * 4096 + s0);
                uint4 hi = *(const uint4*)(bRow + j * 4096 + s1);
                v8i bv = (v8i){(int)lo.x, (int)lo.y, (int)lo.z, (int)lo.w,
                               (int)hi.x, (int)hi.y, (int)hi.z, (int)hi.w};
                acc[j] = __builtin_amdgcn_mfma_scale_f32_32x32x64_f8f6f4(
                    av, bv, acc[j],
                    0 /*fp8*/, 0 /*fp8*/,
                    0, 0x7F7F7F7Fu, 0, 0x7F7F7F7Fu);
            }
        }
        if (kk < 3) __syncthreads();
    }

    // ---- epilogue: out = exp(-(xsq - 2*cross + csq)), float4 NT stores ----
    // C/D 32x32: col = lane&31 -> global col bn + 4*r31 + j (col interleave);
    // row = (reg&3) + 8*(reg>>2) + 4h
    const float4 cs4 = *(const float4*)(csq + bn + 4 * r31);
    const int mbase = bm + 32 * w + 4 * h;

    #pragma unroll
    for (int g = 0; g < 4; ++g) {
        const float4 xs4 = *(const float4*)(xsq + mbase + 8 * g);
        #pragma unroll
        for (int rr = 0; rr < 4; ++rr) {
            const int reg = g * 4 + rr;
            const float xs = (rr == 0) ? xs4.x : (rr == 1) ? xs4.y
                           : (rr == 2) ? xs4.z : xs4.w;
            const int gm = mbase + 8 * g + rr;
            f32x4v o;
            o.x = __expf(-(xs - 2.0f * acc[0][reg] + cs4.x));
            o.y = __expf(-(xs - 2.0f * acc[1][reg] + cs4.y));
            o.z = __expf(-(xs - 2.0f * acc[2][reg] + cs4.z));
            o.w = __expf(-(xs - 2.0f * acc[3][reg] + cs4.w));
            __builtin_nontemporal_store(
                o, (f32x4v*)(out + (size_t)gm * N_DIM + bn + 4 * r31));
        }
    }
}

extern "C" void kernel_launch(void* const* d_in, const int* in_sizes, int n_in,
                              void* d_out, int out_size, void* d_ws, size_t ws_size,
                              hipStream_t stream) {
    const float* X = (const float*)d_in[0];
    const float* C = (const float*)d_in[1];
    float* out = (float*)d_out;

    uint8_t* Apack = (uint8_t*)d_ws;                          // 8 MB
    uint8_t* Bf8 = Apack + (size_t)M_DIM * K_DIM;             // 2 MB
    float* xsq = (float*)(Bf8 + (size_t)N_DIM * K_DIM);       // 64 KB
    float* csq = xsq + M_DIM;                                 // 16 KB

    convert_norm_kernel<<<512 + N_DIM / 4, 256, 0, stream>>>(X, C, Apack, Bf8, xsq, csq);
    rbf_mfma_kernel<<<(M_DIM / 128) * (N_DIM / 128), 256, 0, stream>>>(Apack, Bf8, xsq, csq, out);
}